// Round 7
// baseline (1675.094 us; speedup 1.0000x reference)
//
#include <hip/hip_runtime.h>
#include <hip/hip_bf16.h>

typedef __attribute__((ext_vector_type(8))) short bf16x8;
typedef __attribute__((ext_vector_type(4))) float f32x4;
typedef __attribute__((ext_vector_type(16))) float f32x16;

#define D_MODEL 768
#define N_HEADS 12
#define D_HEAD  64
#define SEQ     4096
#define BATCH   2
#define MROWS   (BATCH * SEQ)          // 8192
#define QKV_N   (3 * D_MODEL)          // 2304
#define NBH     (BATCH * N_HEADS)      // 24
#define SCL     0.18033688011112042f   // (1/8) * log2(e)

// ---------------------------------------------------------------------------
// f32 -> bf16 conversion
// ---------------------------------------------------------------------------
__global__ __launch_bounds__(256) void f32_to_bf16(const float* __restrict__ in,
                                                   unsigned short* __restrict__ out,
                                                   int n4) {
    int i = blockIdx.x * blockDim.x + threadIdx.x;
    if (i >= n4) return;
    const float4 v = *(const float4*)(in + (size_t)i * 4);
    ushort4 o;
    o.x = __bfloat16_as_ushort(__float2bfloat16(v.x));
    o.y = __bfloat16_as_ushort(__float2bfloat16(v.y));
    o.z = __bfloat16_as_ushort(__float2bfloat16(v.z));
    o.w = __bfloat16_as_ushort(__float2bfloat16(v.w));
    *(ushort4*)(out + (size_t)i * 4) = o;
}

// ---------------------------------------------------------------------------
// GEMM: C[M,N] = A[M,K] * B[N,K]^T  (bf16, f32 acc), 128x128 tile, BK=64.
// ---------------------------------------------------------------------------
#define BM 128
#define BN 128
#define BK 64

template <bool OUT_F32>
__global__ __launch_bounds__(256) void gemm_bt(const short* __restrict__ A,
                                               const short* __restrict__ B,
                                               float* __restrict__ Cf,
                                               unsigned short* __restrict__ Cb,
                                               int M, int N, int K) {
    __shared__ __align__(16) short As[BM][BK];
    __shared__ __align__(16) short Bs[BN][BK];

    const int tid  = threadIdx.x;
    const int m0   = blockIdx.y * BM;
    const int n0   = blockIdx.x * BN;
    const int w    = tid >> 6;
    const int lane = tid & 63;
    const int wr   = w >> 1, wc = w & 1;
    const int lr   = lane & 15, lhi = lane >> 4;

    f32x4 acc[4][4];
#pragma unroll
    for (int i = 0; i < 4; i++)
#pragma unroll
        for (int j = 0; j < 4; j++)
#pragma unroll
            for (int e = 0; e < 4; e++) acc[i][j][e] = 0.0f;

    for (int k0 = 0; k0 < K; k0 += BK) {
        __syncthreads();
#pragma unroll
        for (int s = 0; s < 4; ++s) {
            int seg = tid + s * 256;
            int row = seg >> 3;
            int g   = seg & 7;
            int dst = (g ^ (row & 7)) * 8;
            *(bf16x8*)&As[row][dst] = *(const bf16x8*)&A[(size_t)(m0 + row) * K + k0 + g * 8];
            *(bf16x8*)&Bs[row][dst] = *(const bf16x8*)&B[(size_t)(n0 + row) * K + k0 + g * 8];
        }
        __syncthreads();
#pragma unroll
        for (int c = 0; c < 2; ++c) {
            bf16x8 af[4], bfr[4];
#pragma unroll
            for (int mi = 0; mi < 4; mi++) {
                int row = wr * 64 + mi * 16 + lr;
                af[mi] = *(const bf16x8*)&As[row][((c * 4 + lhi) ^ (lr & 7)) * 8];
            }
#pragma unroll
            for (int ni = 0; ni < 4; ni++) {
                int row = wc * 64 + ni * 16 + lr;
                bfr[ni] = *(const bf16x8*)&Bs[row][((c * 4 + lhi) ^ (lr & 7)) * 8];
            }
#pragma unroll
            for (int mi = 0; mi < 4; mi++)
#pragma unroll
                for (int ni = 0; ni < 4; ni++)
                    acc[mi][ni] = __builtin_amdgcn_mfma_f32_16x16x32_bf16(af[mi], bfr[ni], acc[mi][ni], 0, 0, 0);
        }
    }

#pragma unroll
    for (int mi = 0; mi < 4; mi++)
#pragma unroll
        for (int ni = 0; ni < 4; ni++)
#pragma unroll
            for (int r = 0; r < 4; r++) {
                int row = m0 + wr * 64 + mi * 16 + lhi * 4 + r;
                int col = n0 + wc * 64 + ni * 16 + lr;
                float v = acc[mi][ni][r];
                if (OUT_F32)
                    Cf[(size_t)row * N + col] = v;
                else
                    Cb[(size_t)row * N + col] = __bfloat16_as_ushort(__float2bfloat16(v));
            }
}

// ---------------------------------------------------------------------------
// V transpose: qkv V-region (b,t,h,d) -> vt[bh*64+d][t]  (bf16)
// ---------------------------------------------------------------------------
__global__ __launch_bounds__(256) void v_transpose(const short* __restrict__ qkv,
                                                   short* __restrict__ vt) {
    __shared__ short S[64][72];
    const int tid = threadIdx.x;
    const int t0  = blockIdx.x * 64;
    const int bh  = blockIdx.y;
    const int b   = bh / N_HEADS, h = bh % N_HEADS;
#pragma unroll
    for (int s = 0; s < 2; s++) {
        int tl = (tid >> 3) + 32 * s, dg = tid & 7;
        *(bf16x8*)&S[tl][dg * 8] =
            *(const bf16x8*)&qkv[((size_t)(b * SEQ + t0 + tl)) * QKV_N + 2 * D_MODEL + h * D_HEAD + dg * 8];
    }
    __syncthreads();
#pragma unroll
    for (int ii = 0; ii < 2; ii++) {
        int d = (tid >> 3) + 32 * ii, tg = tid & 7;
        bf16x8 v;
#pragma unroll
        for (int j = 0; j < 8; j++) v[j] = S[tg * 8 + j][d];
        *(bf16x8*)&vt[((size_t)bh * 64 + d) * SEQ + t0 + tg * 8] = v;
    }
}

// ---------------------------------------------------------------------------
// Flash attention, 32x32 MFMA, LPT-ordered flat grid (heaviest block first).
// Block = 4 waves x 32 q-rows = 128 q-rows.
// S^T = mfma32(K, Q): lane holds S[k=(reg&3)+8*(reg>>2)+4*hi][q=lane&31].
// P -> PV A-frags via cvt_pk_bf16 + v_permlane32_swap (in-register, no LDS).
// ---------------------------------------------------------------------------
__device__ __forceinline__ unsigned cvt_pk_bf16(float lo, float hi) {
    unsigned r;
    asm("v_cvt_pk_bf16_f32 %0, %1, %2" : "=v"(r) : "v"(lo), "v"(hi));
    return r;
}

__global__ __launch_bounds__(256) void attn_fwd(const short* __restrict__ qkv,
                                                const short* __restrict__ vt,
                                                unsigned short* __restrict__ out) {
    __shared__ __align__(16) short Ks[64][64];   // K tile  [kv][d]  (swizzled granules)
    __shared__ __align__(16) short Vs[64][64];   // V^T tile [d][kv] (swizzled granules)

    const int tid  = threadIdx.x;
    const int w    = tid >> 6;
    const int lane = tid & 63;
    const int l31  = lane & 31;
    const int hi   = lane >> 5;
    const int swz  = l31 & 7;
    // LPT: heaviest q-blocks (i=31) dispatch first across all bh
    const int flat = blockIdx.x;
    const int i    = 31 - flat / NBH;
    const int bh   = flat % NBH;
    const int b    = bh / N_HEADS, h = bh % N_HEADS;
    const size_t rowbase = (size_t)b * SEQ;
    const int q0   = i * 128;
    const int qw   = q0 + w * 32;                // wave's first q-row
    const int qg   = qw + l31;                   // this lane's q (softmax-land)
    const int srow = tid >> 3, sg = tid & 7;

    // Q fragments (B operand): qf[c][j] = Q[qg][c*16 + hi*8 + j]
    bf16x8 qf[4];
    {
        const short* qp = &qkv[(rowbase + qg) * QKV_N + h * D_HEAD + hi * 8];
#pragma unroll
        for (int c = 0; c < 4; c++) qf[c] = *(const bf16x8*)&qp[c * 16];
    }

    float m_ = -INFINITY, l_ = 0.0f;
    f32x16 oacc[2];
#pragma unroll
    for (int nd = 0; nd < 2; nd++)
#pragma unroll
        for (int e = 0; e < 16; e++) oacc[nd][e] = 0.0f;

    const int nj = 2 * i + 2;   // kv tiles for this block

    // prefetch tile 0
    bf16x8 kp[2], vp[2];
#pragma unroll
    for (int s = 0; s < 2; s++) {
        int row = srow + 32 * s;
        kp[s] = *(const bf16x8*)&qkv[(rowbase + row) * QKV_N + D_MODEL + h * D_HEAD + sg * 8];
        vp[s] = *(const bf16x8*)&vt[((size_t)bh * 64 + row) * SEQ + sg * 8];
    }

    for (int jt = 0; jt < nj; jt++) {
        const int j0 = jt * 64;
        __syncthreads();
#pragma unroll
        for (int s = 0; s < 2; s++) {
            int row = srow + 32 * s;
            int dst = (sg ^ (row & 7)) * 8;
            *(bf16x8*)&Ks[row][dst] = kp[s];
            *(bf16x8*)&Vs[row][dst] = vp[s];
        }
        {
            int jn = (jt + 1 < nj) ? j0 + 64 : 0;
#pragma unroll
            for (int s = 0; s < 2; s++) {
                int row = srow + 32 * s;
                kp[s] = *(const bf16x8*)&qkv[(rowbase + jn + row) * QKV_N + D_MODEL + h * D_HEAD + sg * 8];
                vp[s] = *(const bf16x8*)&vt[((size_t)bh * 64 + row) * SEQ + jn + sg * 8];
            }
        }
        __syncthreads();

        if (j0 > qw + 31) continue;          // whole tile masked for this wave
        const bool skip1 = (j0 >= qw);       // upper subtile (kv j0+32..j0+63) fully masked

        // ---- S^T = K · Q^T ----
        f32x16 sa0, sa1;
#pragma unroll
        for (int e = 0; e < 16; e++) { sa0[e] = 0.0f; sa1[e] = 0.0f; }
        __builtin_amdgcn_s_setprio(1);
#pragma unroll
        for (int c = 0; c < 4; c++) {
            bf16x8 kf0 = *(const bf16x8*)&Ks[l31][((2 * c + hi) ^ swz) * 8];
            sa0 = __builtin_amdgcn_mfma_f32_32x32x16_bf16(kf0, qf[c], sa0, 0, 0, 0);
        }
        if (!skip1) {
#pragma unroll
            for (int c = 0; c < 4; c++) {
                bf16x8 kf1 = *(const bf16x8*)&Ks[32 + l31][((2 * c + hi) ^ swz) * 8];
                sa1 = __builtin_amdgcn_mfma_f32_32x32x16_bf16(kf1, qf[c], sa1, 0, 0, 0);
            }
        }
        __builtin_amdgcn_s_setprio(0);

        // ---- causal mask ----
        if (j0 + 63 > qw) {
#pragma unroll
            for (int g = 0; g < 4; g++)
#pragma unroll
                for (int r = 0; r < 4; r++) {
                    int kloc = r + 8 * g + 4 * hi;
                    if (j0 + kloc > qg) sa0[g * 4 + r] = -INFINITY;
                    if (!skip1 && j0 + 32 + kloc > qg) sa1[g * 4 + r] = -INFINITY;
                }
        }

        // ---- row max (ILP tree: 4 partials) ----
        float mx;
        {
            float p0 = sa0[0], p1 = sa0[1], p2 = sa0[2], p3 = sa0[3];
#pragma unroll
            for (int e = 4; e < 16; e += 4) {
                p0 = fmaxf(p0, sa0[e]); p1 = fmaxf(p1, sa0[e + 1]);
                p2 = fmaxf(p2, sa0[e + 2]); p3 = fmaxf(p3, sa0[e + 3]);
            }
            if (!skip1) {
#pragma unroll
                for (int e = 0; e < 16; e += 4) {
                    p0 = fmaxf(p0, sa1[e]); p1 = fmaxf(p1, sa1[e + 1]);
                    p2 = fmaxf(p2, sa1[e + 2]); p3 = fmaxf(p3, sa1[e + 3]);
                }
            }
            mx = fmaxf(fmaxf(p0, p1), fmaxf(p2, p3));
        }
        mx = fmaxf(mx, __shfl_xor(mx, 32, 64));
        float smax = mx * SCL;

        // T13 defer-max
        if (!__all(smax <= m_ + 8.0f)) {
            float mnew = fmaxf(m_, smax);
            float corr = __builtin_amdgcn_exp2f(m_ - mnew);
            m_ = mnew;
            l_ *= corr;
#pragma unroll
            for (int g = 0; g < 4; g++)
#pragma unroll
                for (int r = 0; r < 4; r++) {
                    float cf = __shfl(corr, r + 8 * g + 4 * hi, 64);
                    oacc[0][g * 4 + r] *= cf;
                    oacc[1][g * 4 + r] *= cf;
                }
        }

        // ---- P = exp2(S*SCL - m), row-sum (4 partial accumulators) ----
        float s0 = 0.f, s1 = 0.f, s2 = 0.f, s3 = 0.f;
#pragma unroll
        for (int e = 0; e < 16; e += 4) {
            float a0 = __builtin_amdgcn_exp2f(fmaf(sa0[e], SCL, -m_));
            float a1 = __builtin_amdgcn_exp2f(fmaf(sa0[e + 1], SCL, -m_));
            float a2 = __builtin_amdgcn_exp2f(fmaf(sa0[e + 2], SCL, -m_));
            float a3 = __builtin_amdgcn_exp2f(fmaf(sa0[e + 3], SCL, -m_));
            sa0[e] = a0; sa0[e + 1] = a1; sa0[e + 2] = a2; sa0[e + 3] = a3;
            s0 += a0; s1 += a1; s2 += a2; s3 += a3;
        }
        if (!skip1) {
#pragma unroll
            for (int e = 0; e < 16; e += 4) {
                float a0 = __builtin_amdgcn_exp2f(fmaf(sa1[e], SCL, -m_));
                float a1 = __builtin_amdgcn_exp2f(fmaf(sa1[e + 1], SCL, -m_));
                float a2 = __builtin_amdgcn_exp2f(fmaf(sa1[e + 2], SCL, -m_));
                float a3 = __builtin_amdgcn_exp2f(fmaf(sa1[e + 3], SCL, -m_));
                sa1[e] = a0; sa1[e + 1] = a1; sa1[e + 2] = a2; sa1[e + 3] = a3;
                s0 += a0; s1 += a1; s2 += a2; s3 += a3;
            }
        }
        float ls = (s0 + s1) + (s2 + s3);
        ls += __shfl_xor(ls, 32, 64);
        l_ += ls;

        // ---- pack P to bf16, redistribute via permlane32_swap -> A-frags ----
        bf16x8 pa[4];
#pragma unroll
        for (int ks = 0; ks < 2; ks++) {
            if (ks == 1 && skip1) break;
            unsigned X[4], U[4];
#pragma unroll
            for (int g = 0; g < 4; g++) {
                X[g] = cvt_pk_bf16(ks ? sa1[4 * g + 0] : sa0[4 * g + 0],
                                   ks ? sa1[4 * g + 1] : sa0[4 * g + 1]);
                U[g] = cvt_pk_bf16(ks ? sa1[4 * g + 2] : sa0[4 * g + 2],
                                   ks ? sa1[4 * g + 3] : sa0[4 * g + 3]);
            }
            asm("v_permlane32_swap_b32 %0, %1" : "+v"(X[0]), "+v"(X[1]));
            asm("v_permlane32_swap_b32 %0, %1" : "+v"(U[0]), "+v"(U[1]));
            asm("v_permlane32_swap_b32 %0, %1" : "+v"(X[2]), "+v"(X[3]));
            asm("v_permlane32_swap_b32 %0, %1" : "+v"(U[2]), "+v"(U[3]));
            union { unsigned u[4]; bf16x8 v; } p0, p1;
            p0.u[0] = X[0]; p0.u[1] = U[0]; p0.u[2] = X[1]; p0.u[3] = U[1];
            p1.u[0] = X[2]; p1.u[1] = U[2]; p1.u[2] = X[3]; p1.u[3] = U[3];
            pa[ks * 2 + 0] = p0.v;
            pa[ks * 2 + 1] = p1.v;
        }

        // ---- O += P · V ----
        const int nkc = skip1 ? 2 : 4;
        __builtin_amdgcn_s_setprio(1);
#pragma unroll
        for (int nd = 0; nd < 2; nd++) {
#pragma unroll 4
            for (int kc = 0; kc < nkc; kc++) {
                bf16x8 vb = *(const bf16x8*)&Vs[nd * 32 + l31][((kc * 2 + hi) ^ swz) * 8];
                oacc[nd] = __builtin_amdgcn_mfma_f32_32x32x16_bf16(pa[kc], vb, oacc[nd], 0, 0, 0);
            }
        }
        __builtin_amdgcn_s_setprio(0);
    }

    // ---- epilogue ----
    float li = 1.0f / l_;
    float lT[16];
#pragma unroll
    for (int g = 0; g < 4; g++)
#pragma unroll
        for (int r = 0; r < 4; r++) lT[g * 4 + r] = __shfl(li, r + 8 * g + 4 * hi, 64);
#pragma unroll
    for (int nd = 0; nd < 2; nd++)
#pragma unroll
        for (int g = 0; g < 4; g++)
#pragma unroll
            for (int r = 0; r < 4; r++) {
                int qrow = qw + r + 8 * g + 4 * hi;
                out[(rowbase + qrow) * D_MODEL + h * D_HEAD + nd * 32 + l31] =
                    __bfloat16_as_ushort(__float2bfloat16(oacc[nd][g * 4 + r] * lT[g * 4 + r]));
            }
}

// ---------------------------------------------------------------------------
extern "C" void kernel_launch(void* const* d_in, const int* in_sizes, int n_in,
                              void* d_out, int out_size, void* d_ws, size_t ws_size,
                              hipStream_t stream) {
    const float* x     = (const float*)d_in[0];
    const float* w_qkv = (const float*)d_in[1];
    const float* w_out = (const float*)d_in[2];
    float* outp        = (float*)d_out;

    char* ws = (char*)d_ws;
    size_t off = 0;
    auto alloc = [&](size_t bytes) -> void* {
        void* p = ws + off;
        off = (off + bytes + 255) & ~(size_t)255;
        return p;
    };
    unsigned short* xb    = (unsigned short*)alloc((size_t)MROWS * D_MODEL * 2);  // also attn out
    unsigned short* wqkvb = (unsigned short*)alloc((size_t)QKV_N * D_MODEL * 2);
    unsigned short* woutb = (unsigned short*)alloc((size_t)D_MODEL * D_MODEL * 2);
    unsigned short* qkvb  = (unsigned short*)alloc((size_t)MROWS * QKV_N * 2);
    unsigned short* vtb   = (unsigned short*)alloc((size_t)BATCH * N_HEADS * D_HEAD * SEQ * 2);

    {
        int n4 = MROWS * D_MODEL / 4;
        f32_to_bf16<<<(n4 + 255) / 256, 256, 0, stream>>>(x, xb, n4);
        n4 = QKV_N * D_MODEL / 4;
        f32_to_bf16<<<(n4 + 255) / 256, 256, 0, stream>>>(w_qkv, wqkvb, n4);
        n4 = D_MODEL * D_MODEL / 4;
        f32_to_bf16<<<(n4 + 255) / 256, 256, 0, stream>>>(w_out, woutb, n4);
    }

    // qkv = x @ w_qkv^T   (M=8192, N=2304, K=768) -> bf16
    gemm_bt<false><<<dim3(QKV_N / BN, MROWS / BM), 256, 0, stream>>>(
        (const short*)xb, (const short*)wqkvb, nullptr, qkvb, MROWS, QKV_N, D_MODEL);

    // V transpose: (b,t,h,d) -> [bh*64+d][t]
    v_transpose<<<dim3(SEQ / 64, BATCH * N_HEADS), 256, 0, stream>>>((const short*)qkvb, (short*)vtb);

    // attention: flat LPT grid, heaviest q-blocks first
    attn_fwd<<<dim3(32 * NBH), 256, 0, stream>>>(
        (const short*)qkvb, (const short*)vtb, xb);

    // out = attn @ w_out^T  (M=8192, N=768, K=768) -> f32
    gemm_bt<true><<<dim3(D_MODEL / BN, MROWS / BM), 256, 0, stream>>>(
        (const short*)xb, (const short*)woutb, outp, nullptr, MROWS, D_MODEL, D_MODEL);
}

// Round 8
// 212.755 us; speedup vs baseline: 7.8733x; 7.8733x over previous
//
#include <hip/hip_runtime.h>
#include <hip/hip_bf16.h>

typedef __attribute__((ext_vector_type(8))) short bf16x8;
typedef __attribute__((ext_vector_type(4))) float f32x4;
typedef __attribute__((ext_vector_type(16))) float f32x16;

#define D_MODEL 768
#define N_HEADS 12
#define D_HEAD  64
#define SEQ     4096
#define BATCH   2
#define MROWS   (BATCH * SEQ)          // 8192
#define QKV_N   (3 * D_MODEL)          // 2304
#define NBH     (BATCH * N_HEADS)      // 24
#define SCL     0.18033688011112042f   // (1/8) * log2(e)

// LDS granule swizzle: must differ across rows {s, s+8, s+16, s+24} (bank-alias
// group for 128B-stride rows) -> fold bits 3..4 of the row in as well.
#define SWZ(row) ((((row) & 7) ^ (((row) >> 3) & 3)))

// ---------------------------------------------------------------------------
// f32 -> bf16 conversion
// ---------------------------------------------------------------------------
__global__ __launch_bounds__(256) void f32_to_bf16(const float* __restrict__ in,
                                                   unsigned short* __restrict__ out,
                                                   int n4) {
    int i = blockIdx.x * blockDim.x + threadIdx.x;
    if (i >= n4) return;
    const float4 v = *(const float4*)(in + (size_t)i * 4);
    ushort4 o;
    o.x = __bfloat16_as_ushort(__float2bfloat16(v.x));
    o.y = __bfloat16_as_ushort(__float2bfloat16(v.y));
    o.z = __bfloat16_as_ushort(__float2bfloat16(v.z));
    o.w = __bfloat16_as_ushort(__float2bfloat16(v.w));
    *(ushort4*)(out + (size_t)i * 4) = o;
}

// ---------------------------------------------------------------------------
// GEMM: C[M,N] = A[M,K] * B[N,K]^T  (bf16, f32 acc), 128x128 tile, BK=64.
// ---------------------------------------------------------------------------
#define BM 128
#define BN 128
#define BK 64

template <bool OUT_F32>
__global__ __launch_bounds__(256) void gemm_bt(const short* __restrict__ A,
                                               const short* __restrict__ B,
                                               float* __restrict__ Cf,
                                               unsigned short* __restrict__ Cb,
                                               int M, int N, int K) {
    __shared__ __align__(16) short As[BM][BK];
    __shared__ __align__(16) short Bs[BN][BK];

    const int tid  = threadIdx.x;
    const int m0   = blockIdx.y * BM;
    const int n0   = blockIdx.x * BN;
    const int w    = tid >> 6;
    const int lane = tid & 63;
    const int wr   = w >> 1, wc = w & 1;
    const int lr   = lane & 15, lhi = lane >> 4;

    f32x4 acc[4][4];
#pragma unroll
    for (int i = 0; i < 4; i++)
#pragma unroll
        for (int j = 0; j < 4; j++)
#pragma unroll
            for (int e = 0; e < 4; e++) acc[i][j][e] = 0.0f;

    for (int k0 = 0; k0 < K; k0 += BK) {
        __syncthreads();
#pragma unroll
        for (int s = 0; s < 4; ++s) {
            int seg = tid + s * 256;
            int row = seg >> 3;
            int g   = seg & 7;
            int dst = (g ^ (row & 7)) * 8;
            *(bf16x8*)&As[row][dst] = *(const bf16x8*)&A[(size_t)(m0 + row) * K + k0 + g * 8];
            *(bf16x8*)&Bs[row][dst] = *(const bf16x8*)&B[(size_t)(n0 + row) * K + k0 + g * 8];
        }
        __syncthreads();
#pragma unroll
        for (int c = 0; c < 2; ++c) {
            bf16x8 af[4], bfr[4];
#pragma unroll
            for (int mi = 0; mi < 4; mi++) {
                int row = wr * 64 + mi * 16 + lr;
                af[mi] = *(const bf16x8*)&As[row][((c * 4 + lhi) ^ (lr & 7)) * 8];
            }
#pragma unroll
            for (int ni = 0; ni < 4; ni++) {
                int row = wc * 64 + ni * 16 + lr;
                bfr[ni] = *(const bf16x8*)&Bs[row][((c * 4 + lhi) ^ (lr & 7)) * 8];
            }
#pragma unroll
            for (int mi = 0; mi < 4; mi++)
#pragma unroll
                for (int ni = 0; ni < 4; ni++)
                    acc[mi][ni] = __builtin_amdgcn_mfma_f32_16x16x32_bf16(af[mi], bfr[ni], acc[mi][ni], 0, 0, 0);
        }
    }

#pragma unroll
    for (int mi = 0; mi < 4; mi++)
#pragma unroll
        for (int ni = 0; ni < 4; ni++)
#pragma unroll
            for (int r = 0; r < 4; r++) {
                int row = m0 + wr * 64 + mi * 16 + lhi * 4 + r;
                int col = n0 + wc * 64 + ni * 16 + lr;
                float v = acc[mi][ni][r];
                if (OUT_F32)
                    Cf[(size_t)row * N + col] = v;
                else
                    Cb[(size_t)row * N + col] = __bfloat16_as_ushort(__float2bfloat16(v));
            }
}

// ---------------------------------------------------------------------------
// V transpose: qkv V-region (b,t,h,d) -> vt[bh*64+d][t]  (bf16)
// ---------------------------------------------------------------------------
__global__ __launch_bounds__(256) void v_transpose(const short* __restrict__ qkv,
                                                   short* __restrict__ vt) {
    __shared__ short S[64][72];
    const int tid = threadIdx.x;
    const int t0  = blockIdx.x * 64;
    const int bh  = blockIdx.y;
    const int b   = bh / N_HEADS, h = bh % N_HEADS;
#pragma unroll
    for (int s = 0; s < 2; s++) {
        int tl = (tid >> 3) + 32 * s, dg = tid & 7;
        *(bf16x8*)&S[tl][dg * 8] =
            *(const bf16x8*)&qkv[((size_t)(b * SEQ + t0 + tl)) * QKV_N + 2 * D_MODEL + h * D_HEAD + dg * 8];
    }
    __syncthreads();
#pragma unroll
    for (int ii = 0; ii < 2; ii++) {
        int d = (tid >> 3) + 32 * ii, tg = tid & 7;
        bf16x8 v;
#pragma unroll
        for (int j = 0; j < 8; j++) v[j] = S[tg * 8 + j][d];
        *(bf16x8*)&vt[((size_t)bh * 64 + d) * SEQ + t0 + tg * 8] = v;
    }
}

// ---------------------------------------------------------------------------
// Flash attention, 32x32 MFMA, LPT-ordered flat grid (heaviest block first).
// Block = 4 waves x 32 q-rows = 128 q-rows.
// S^T = mfma32(K, Q): lane holds S[k=(reg&3)+8*(reg>>2)+4*hi][q=lane&31].
// P -> PV A-frags via cvt_pk_bf16 + v_permlane32_swap. ALL register arrays
// statically indexed (rule #20).
// ---------------------------------------------------------------------------
__device__ __forceinline__ unsigned cvt_pk_bf16(float lo, float hi) {
    unsigned r;
    asm("v_cvt_pk_bf16_f32 %0, %1, %2" : "=v"(r) : "v"(lo), "v"(hi));
    return r;
}

__global__ __launch_bounds__(256) void attn_fwd(const short* __restrict__ qkv,
                                                const short* __restrict__ vt,
                                                unsigned short* __restrict__ out) {
    __shared__ __align__(16) short Ks[64][64];   // K tile  [kv][d]  (swizzled granules)
    __shared__ __align__(16) short Vs[64][64];   // V^T tile [d][kv] (swizzled granules)

    const int tid  = threadIdx.x;
    const int w    = tid >> 6;
    const int lane = tid & 63;
    const int l31  = lane & 31;
    const int hi   = lane >> 5;
    const int swzk = SWZ(l31);                   // K rows l31 / 32+l31 share SWZ
    // LPT: heaviest q-blocks (i=31) dispatch first across all bh
    const int flat = blockIdx.x;
    const int i    = 31 - flat / NBH;
    const int bh   = flat % NBH;
    const int b    = bh / N_HEADS, h = bh % N_HEADS;
    const size_t rowbase = (size_t)b * SEQ;
    const int q0   = i * 128;
    const int qw   = q0 + w * 32;                // wave's first q-row
    const int qg   = qw + l31;                   // this lane's q (softmax-land)
    const int srow = tid >> 3, sg = tid & 7;

    // Q fragments (B operand): qf[c][j] = Q[qg][c*16 + hi*8 + j]
    bf16x8 qf[4];
    {
        const short* qp = &qkv[(rowbase + qg) * QKV_N + h * D_HEAD + hi * 8];
#pragma unroll
        for (int c = 0; c < 4; c++) qf[c] = *(const bf16x8*)&qp[c * 16];
    }

    float m_ = -INFINITY, l_ = 0.0f;
    f32x16 oacc[2];
#pragma unroll
    for (int nd = 0; nd < 2; nd++)
#pragma unroll
        for (int e = 0; e < 16; e++) oacc[nd][e] = 0.0f;

    const int nj = 2 * i + 2;   // kv tiles for this block

    // prefetch tile 0
    bf16x8 kp[2], vp[2];
#pragma unroll
    for (int s = 0; s < 2; s++) {
        int row = srow + 32 * s;
        kp[s] = *(const bf16x8*)&qkv[(rowbase + row) * QKV_N + D_MODEL + h * D_HEAD + sg * 8];
        vp[s] = *(const bf16x8*)&vt[((size_t)bh * 64 + row) * SEQ + sg * 8];
    }

    for (int jt = 0; jt < nj; jt++) {
        const int j0 = jt * 64;
        __syncthreads();
#pragma unroll
        for (int s = 0; s < 2; s++) {
            int row = srow + 32 * s;
            int dst = (sg ^ SWZ(row)) * 8;
            *(bf16x8*)&Ks[row][dst] = kp[s];
            *(bf16x8*)&Vs[row][dst] = vp[s];
        }
        {
            int jn = (jt + 1 < nj) ? j0 + 64 : 0;
#pragma unroll
            for (int s = 0; s < 2; s++) {
                int row = srow + 32 * s;
                kp[s] = *(const bf16x8*)&qkv[(rowbase + jn + row) * QKV_N + D_MODEL + h * D_HEAD + sg * 8];
                vp[s] = *(const bf16x8*)&vt[((size_t)bh * 64 + row) * SEQ + jn + sg * 8];
            }
        }
        __syncthreads();

        if (j0 > qw + 31) continue;          // whole tile masked for this wave
        const bool skip1 = (j0 >= qw);       // upper subtile fully masked

        // ---- S^T = K · Q^T ----
        f32x16 sa0, sa1;
#pragma unroll
        for (int e = 0; e < 16; e++) { sa0[e] = 0.0f; sa1[e] = 0.0f; }
        __builtin_amdgcn_s_setprio(1);
#pragma unroll
        for (int c = 0; c < 4; c++) {
            bf16x8 kf0 = *(const bf16x8*)&Ks[l31][((2 * c + hi) ^ swzk) * 8];
            sa0 = __builtin_amdgcn_mfma_f32_32x32x16_bf16(kf0, qf[c], sa0, 0, 0, 0);
        }
        if (!skip1) {
#pragma unroll
            for (int c = 0; c < 4; c++) {
                bf16x8 kf1 = *(const bf16x8*)&Ks[32 + l31][((2 * c + hi) ^ swzk) * 8];
                sa1 = __builtin_amdgcn_mfma_f32_32x32x16_bf16(kf1, qf[c], sa1, 0, 0, 0);
            }
        }
        __builtin_amdgcn_s_setprio(0);

        // ---- causal mask ----
        if (j0 + 63 > qw) {
#pragma unroll
            for (int g = 0; g < 4; g++)
#pragma unroll
                for (int r = 0; r < 4; r++) {
                    int kloc = r + 8 * g + 4 * hi;
                    if (j0 + kloc > qg) sa0[g * 4 + r] = -INFINITY;
                    if (!skip1 && j0 + 32 + kloc > qg) sa1[g * 4 + r] = -INFINITY;
                }
        }

        // ---- row max (ILP tree: 4 partials) ----
        float mx;
        {
            float p0 = sa0[0], p1 = sa0[1], p2 = sa0[2], p3 = sa0[3];
#pragma unroll
            for (int e = 4; e < 16; e += 4) {
                p0 = fmaxf(p0, sa0[e]); p1 = fmaxf(p1, sa0[e + 1]);
                p2 = fmaxf(p2, sa0[e + 2]); p3 = fmaxf(p3, sa0[e + 3]);
            }
            if (!skip1) {
#pragma unroll
                for (int e = 0; e < 16; e += 4) {
                    p0 = fmaxf(p0, sa1[e]); p1 = fmaxf(p1, sa1[e + 1]);
                    p2 = fmaxf(p2, sa1[e + 2]); p3 = fmaxf(p3, sa1[e + 3]);
                }
            }
            mx = fmaxf(fmaxf(p0, p1), fmaxf(p2, p3));
        }
        mx = fmaxf(mx, __shfl_xor(mx, 32, 64));
        float smax = mx * SCL;

        // T13 defer-max
        if (!__all(smax <= m_ + 8.0f)) {
            float mnew = fmaxf(m_, smax);
            float corr = __builtin_amdgcn_exp2f(m_ - mnew);
            m_ = mnew;
            l_ *= corr;
#pragma unroll
            for (int g = 0; g < 4; g++)
#pragma unroll
                for (int r = 0; r < 4; r++) {
                    float cf = __shfl(corr, r + 8 * g + 4 * hi, 64);
                    oacc[0][g * 4 + r] *= cf;
                    oacc[1][g * 4 + r] *= cf;
                }
        }

        // ---- P = exp2(S*SCL - m), row-sum (4 partial accumulators) ----
        float s0 = 0.f, s1 = 0.f, s2 = 0.f, s3 = 0.f;
#pragma unroll
        for (int e = 0; e < 16; e += 4) {
            float a0 = __builtin_amdgcn_exp2f(fmaf(sa0[e], SCL, -m_));
            float a1 = __builtin_amdgcn_exp2f(fmaf(sa0[e + 1], SCL, -m_));
            float a2 = __builtin_amdgcn_exp2f(fmaf(sa0[e + 2], SCL, -m_));
            float a3 = __builtin_amdgcn_exp2f(fmaf(sa0[e + 3], SCL, -m_));
            sa0[e] = a0; sa0[e + 1] = a1; sa0[e + 2] = a2; sa0[e + 3] = a3;
            s0 += a0; s1 += a1; s2 += a2; s3 += a3;
        }
        if (!skip1) {
#pragma unroll
            for (int e = 0; e < 16; e += 4) {
                float a0 = __builtin_amdgcn_exp2f(fmaf(sa1[e], SCL, -m_));
                float a1 = __builtin_amdgcn_exp2f(fmaf(sa1[e + 1], SCL, -m_));
                float a2 = __builtin_amdgcn_exp2f(fmaf(sa1[e + 2], SCL, -m_));
                float a3 = __builtin_amdgcn_exp2f(fmaf(sa1[e + 3], SCL, -m_));
                sa1[e] = a0; sa1[e + 1] = a1; sa1[e + 2] = a2; sa1[e + 3] = a3;
                s0 += a0; s1 += a1; s2 += a2; s3 += a3;
            }
        }
        float ls = (s0 + s1) + (s2 + s3);
        ls += __shfl_xor(ls, 32, 64);
        l_ += ls;

        // ---- pack P -> bf16 A-frags (STATIC indices only; named pa0..pa3) ----
        bf16x8 pa0, pa1, pa2, pa3;
        {
            unsigned X[4], U[4];
#pragma unroll
            for (int g = 0; g < 4; g++) {
                X[g] = cvt_pk_bf16(sa0[4 * g + 0], sa0[4 * g + 1]);
                U[g] = cvt_pk_bf16(sa0[4 * g + 2], sa0[4 * g + 3]);
            }
            asm("v_permlane32_swap_b32 %0, %1" : "+v"(X[0]), "+v"(X[1]));
            asm("v_permlane32_swap_b32 %0, %1" : "+v"(U[0]), "+v"(U[1]));
            asm("v_permlane32_swap_b32 %0, %1" : "+v"(X[2]), "+v"(X[3]));
            asm("v_permlane32_swap_b32 %0, %1" : "+v"(U[2]), "+v"(U[3]));
            union { unsigned u[4]; bf16x8 v; } q0_, q1_;
            q0_.u[0] = X[0]; q0_.u[1] = U[0]; q0_.u[2] = X[1]; q0_.u[3] = U[1];
            q1_.u[0] = X[2]; q1_.u[1] = U[2]; q1_.u[2] = X[3]; q1_.u[3] = U[3];
            pa0 = q0_.v; pa1 = q1_.v;
        }
        if (!skip1) {
            unsigned X[4], U[4];
#pragma unroll
            for (int g = 0; g < 4; g++) {
                X[g] = cvt_pk_bf16(sa1[4 * g + 0], sa1[4 * g + 1]);
                U[g] = cvt_pk_bf16(sa1[4 * g + 2], sa1[4 * g + 3]);
            }
            asm("v_permlane32_swap_b32 %0, %1" : "+v"(X[0]), "+v"(X[1]));
            asm("v_permlane32_swap_b32 %0, %1" : "+v"(U[0]), "+v"(U[1]));
            asm("v_permlane32_swap_b32 %0, %1" : "+v"(X[2]), "+v"(X[3]));
            asm("v_permlane32_swap_b32 %0, %1" : "+v"(U[2]), "+v"(U[3]));
            union { unsigned u[4]; bf16x8 v; } q0_, q1_;
            q0_.u[0] = X[0]; q0_.u[1] = U[0]; q0_.u[2] = X[1]; q0_.u[3] = U[1];
            q1_.u[0] = X[2]; q1_.u[1] = U[2]; q1_.u[2] = X[3]; q1_.u[3] = U[3];
            pa2 = q0_.v; pa3 = q1_.v;
        } else {
            pa2 = pa0; pa3 = pa1;   // never used (guarded below); keep defined
        }

        // ---- O += P · V  (explicit, static; kc>=2 under uniform guard) ----
        __builtin_amdgcn_s_setprio(1);
#pragma unroll
        for (int nd = 0; nd < 2; nd++) {
            const int vrow = nd * 32 + l31;
            const int vswz = SWZ(vrow);
            bf16x8 vb0 = *(const bf16x8*)&Vs[vrow][((0 + hi) ^ vswz) * 8];
            oacc[nd] = __builtin_amdgcn_mfma_f32_32x32x16_bf16(pa0, vb0, oacc[nd], 0, 0, 0);
            bf16x8 vb1 = *(const bf16x8*)&Vs[vrow][((2 + hi) ^ vswz) * 8];
            oacc[nd] = __builtin_amdgcn_mfma_f32_32x32x16_bf16(pa1, vb1, oacc[nd], 0, 0, 0);
            if (!skip1) {
                bf16x8 vb2 = *(const bf16x8*)&Vs[vrow][((4 + hi) ^ vswz) * 8];
                oacc[nd] = __builtin_amdgcn_mfma_f32_32x32x16_bf16(pa2, vb2, oacc[nd], 0, 0, 0);
                bf16x8 vb3 = *(const bf16x8*)&Vs[vrow][((6 + hi) ^ vswz) * 8];
                oacc[nd] = __builtin_amdgcn_mfma_f32_32x32x16_bf16(pa3, vb3, oacc[nd], 0, 0, 0);
            }
        }
        __builtin_amdgcn_s_setprio(0);
    }

    // ---- epilogue ----
    float li = 1.0f / l_;
    float lT[16];
#pragma unroll
    for (int g = 0; g < 4; g++)
#pragma unroll
        for (int r = 0; r < 4; r++) lT[g * 4 + r] = __shfl(li, r + 8 * g + 4 * hi, 64);
#pragma unroll
    for (int nd = 0; nd < 2; nd++)
#pragma unroll
        for (int g = 0; g < 4; g++)
#pragma unroll
            for (int r = 0; r < 4; r++) {
                int qrow = qw + r + 8 * g + 4 * hi;
                out[(rowbase + qrow) * D_MODEL + h * D_HEAD + nd * 32 + l31] =
                    __bfloat16_as_ushort(__float2bfloat16(oacc[nd][g * 4 + r] * lT[g * 4 + r]));
            }
}

// ---------------------------------------------------------------------------
extern "C" void kernel_launch(void* const* d_in, const int* in_sizes, int n_in,
                              void* d_out, int out_size, void* d_ws, size_t ws_size,
                              hipStream_t stream) {
    const float* x     = (const float*)d_in[0];
    const float* w_qkv = (const float*)d_in[1];
    const float* w_out = (const float*)d_in[2];
    float* outp        = (float*)d_out;

    char* ws = (char*)d_ws;
    size_t off = 0;
    auto alloc = [&](size_t bytes) -> void* {
        void* p = ws + off;
        off = (off + bytes + 255) & ~(size_t)255;
        return p;
    };
    unsigned short* xb    = (unsigned short*)alloc((size_t)MROWS * D_MODEL * 2);  // also attn out
    unsigned short* wqkvb = (unsigned short*)alloc((size_t)QKV_N * D_MODEL * 2);
    unsigned short* woutb = (unsigned short*)alloc((size_t)D_MODEL * D_MODEL * 2);
    unsigned short* qkvb  = (unsigned short*)alloc((size_t)MROWS * QKV_N * 2);
    unsigned short* vtb   = (unsigned short*)alloc((size_t)BATCH * N_HEADS * D_HEAD * SEQ * 2);

    {
        int n4 = MROWS * D_MODEL / 4;
        f32_to_bf16<<<(n4 + 255) / 256, 256, 0, stream>>>(x, xb, n4);
        n4 = QKV_N * D_MODEL / 4;
        f32_to_bf16<<<(n4 + 255) / 256, 256, 0, stream>>>(w_qkv, wqkvb, n4);
        n4 = D_MODEL * D_MODEL / 4;
        f32_to_bf16<<<(n4 + 255) / 256, 256, 0, stream>>>(w_out, woutb, n4);
    }

    // qkv = x @ w_qkv^T   (M=8192, N=2304, K=768) -> bf16
    gemm_bt<false><<<dim3(QKV_N / BN, MROWS / BM), 256, 0, stream>>>(
        (const short*)xb, (const short*)wqkvb, nullptr, qkvb, MROWS, QKV_N, D_MODEL);

    // V transpose: (b,t,h,d) -> [bh*64+d][t]
    v_transpose<<<dim3(SEQ / 64, BATCH * N_HEADS), 256, 0, stream>>>((const short*)qkvb, (short*)vtb);

    // attention: flat LPT grid, heaviest q-blocks first
    attn_fwd<<<dim3(32 * NBH), 256, 0, stream>>>(
        (const short*)qkvb, (const short*)vtb, xb);

    // out = attn @ w_out^T  (M=8192, N=768, K=768) -> f32
    gemm_bt<true><<<dim3(D_MODEL / BN, MROWS / BM), 256, 0, stream>>>(
        (const short*)xb, (const short*)woutb, outp, nullptr, MROWS, D_MODEL, D_MODEL);
}

// Round 9
// 206.321 us; speedup vs baseline: 8.1189x; 1.0312x over previous
//
#include <hip/hip_runtime.h>
#include <hip/hip_bf16.h>

typedef __attribute__((ext_vector_type(8))) short bf16x8;
typedef __attribute__((ext_vector_type(4))) float f32x4;
typedef __attribute__((ext_vector_type(16))) float f32x16;

#define D_MODEL 768
#define N_HEADS 12
#define D_HEAD  64
#define SEQ     4096
#define BATCH   2
#define MROWS   (BATCH * SEQ)          // 8192
#define QKV_N   (3 * D_MODEL)          // 2304
#define NBH     (BATCH * N_HEADS)      // 24
#define SCL     0.18033688011112042f   // (1/8) * log2(e)

// LDS granule swizzle for attn tiles (rows {s,s+8,s+16,s+24} must differ)
#define SWZ(row) ((((row) & 7) ^ (((row) >> 3) & 3)))

// global_load_lds helpers (LDS dest is wave-uniform; lane adds lane*16)
#define GLOAD_LDS16(gsrc, ldst) \
    __builtin_amdgcn_global_load_lds( \
        (const __attribute__((address_space(1))) int*)(gsrc), \
        (__attribute__((address_space(3))) int*)(ldst), 16, 0, 0)

// ---------------------------------------------------------------------------
// fused f32 -> bf16 conversion for all three inputs
// ---------------------------------------------------------------------------
__global__ __launch_bounds__(256) void cvt_all(const float* __restrict__ x,  unsigned short* __restrict__ xb,  int nx4,
                                               const float* __restrict__ wq, unsigned short* __restrict__ wqb, int nq4,
                                               const float* __restrict__ wo, unsigned short* __restrict__ wob, int no4) {
    int i = blockIdx.x * blockDim.x + threadIdx.x;
    const float* in;
    unsigned short* out;
    int idx;
    if (i < nx4)                   { in = x;  out = xb;  idx = i; }
    else if (i < nx4 + nq4)        { in = wq; out = wqb; idx = i - nx4; }
    else if (i < nx4 + nq4 + no4)  { in = wo; out = wob; idx = i - nx4 - nq4; }
    else return;
    const float4 v = *(const float4*)(in + (size_t)idx * 4);
    ushort4 o;
    o.x = __bfloat16_as_ushort(__float2bfloat16(v.x));
    o.y = __bfloat16_as_ushort(__float2bfloat16(v.y));
    o.z = __bfloat16_as_ushort(__float2bfloat16(v.z));
    o.w = __bfloat16_as_ushort(__float2bfloat16(v.w));
    *(ushort4*)(out + (size_t)idx * 4) = o;
}

// ---------------------------------------------------------------------------
// GEMM: C[M,N] = A[M,K] * B[N,K]^T  (bf16, f32 acc), 128x128 tile, BK=64.
// Staging: global_load_lds width=16, linear LDS dest + pre-swizzled global
// source (rule #21). Read side applies the same XOR on the granule index.
// ---------------------------------------------------------------------------
#define BM 128
#define BN 128
#define BK 64

template <bool OUT_F32>
__global__ __launch_bounds__(256) void gemm_bt(const short* __restrict__ A,
                                               const short* __restrict__ B,
                                               float* __restrict__ Cf,
                                               unsigned short* __restrict__ Cb,
                                               int M, int N, int K) {
    __shared__ __align__(16) short As[BM][BK];
    __shared__ __align__(16) short Bs[BN][BK];

    const int tid  = threadIdx.x;
    const int m0   = blockIdx.y * BM;
    const int n0   = blockIdx.x * BN;
    const int w    = tid >> 6;
    const int lane = tid & 63;
    const int wr   = w >> 1, wc = w & 1;
    const int lr   = lane & 15, lhi = lane >> 4;

    // staging geometry: call s of wave w fills LDS granules [(w*4+s)*64 + lane];
    // granule idx -> row = idx>>3, logical granule g = idx&7; global granule
    // ga = g ^ (row&7) (inverse swizzle pre-applied on the source address).
    int srow[4], sga[4];
#pragma unroll
    for (int s = 0; s < 4; s++) {
        int idx = (w * 4 + s) * 64 + lane;
        srow[s] = idx >> 3;
        sga[s]  = (idx & 7) ^ (srow[s] & 7);
    }

    f32x4 acc[4][4];
#pragma unroll
    for (int i = 0; i < 4; i++)
#pragma unroll
        for (int j = 0; j < 4; j++)
#pragma unroll
            for (int e = 0; e < 4; e++) acc[i][j][e] = 0.0f;

    for (int k0 = 0; k0 < K; k0 += BK) {
        // issue async global->LDS for this K-tile
#pragma unroll
        for (int s = 0; s < 4; s++) {
            GLOAD_LDS16(&A[(size_t)(m0 + srow[s]) * K + k0 + sga[s] * 8],
                        (short*)As + (w * 4 + s) * 512);
            GLOAD_LDS16(&B[(size_t)(n0 + srow[s]) * K + k0 + sga[s] * 8],
                        (short*)Bs + (w * 4 + s) * 512);
        }
        __syncthreads();   // drains vmcnt(0): LDS tile ready
#pragma unroll
        for (int c = 0; c < 2; ++c) {
            bf16x8 af[4], bfr[4];
#pragma unroll
            for (int mi = 0; mi < 4; mi++) {
                int row = wr * 64 + mi * 16 + lr;
                af[mi] = *(const bf16x8*)&As[row][((c * 4 + lhi) ^ (lr & 7)) * 8];
            }
#pragma unroll
            for (int ni = 0; ni < 4; ni++) {
                int row = wc * 64 + ni * 16 + lr;
                bfr[ni] = *(const bf16x8*)&Bs[row][((c * 4 + lhi) ^ (lr & 7)) * 8];
            }
#pragma unroll
            for (int mi = 0; mi < 4; mi++)
#pragma unroll
                for (int ni = 0; ni < 4; ni++)
                    acc[mi][ni] = __builtin_amdgcn_mfma_f32_16x16x32_bf16(af[mi], bfr[ni], acc[mi][ni], 0, 0, 0);
        }
        __syncthreads();   // all reads done before next tile overwrites
    }

#pragma unroll
    for (int mi = 0; mi < 4; mi++)
#pragma unroll
        for (int ni = 0; ni < 4; ni++)
#pragma unroll
            for (int r = 0; r < 4; r++) {
                int row = m0 + wr * 64 + mi * 16 + lhi * 4 + r;
                int col = n0 + wc * 64 + ni * 16 + lr;
                float v = acc[mi][ni][r];
                if (OUT_F32)
                    Cf[(size_t)row * N + col] = v;
                else
                    Cb[(size_t)row * N + col] = __bfloat16_as_ushort(__float2bfloat16(v));
            }
}

// ---------------------------------------------------------------------------
// V transpose: qkv V-region (b,t,h,d) -> vt[bh*64+d][t]  (bf16)
// ---------------------------------------------------------------------------
__global__ __launch_bounds__(256) void v_transpose(const short* __restrict__ qkv,
                                                   short* __restrict__ vt) {
    __shared__ short S[64][72];
    const int tid = threadIdx.x;
    const int t0  = blockIdx.x * 64;
    const int bh  = blockIdx.y;
    const int b   = bh / N_HEADS, h = bh % N_HEADS;
#pragma unroll
    for (int s = 0; s < 2; s++) {
        int tl = (tid >> 3) + 32 * s, dg = tid & 7;
        *(bf16x8*)&S[tl][dg * 8] =
            *(const bf16x8*)&qkv[((size_t)(b * SEQ + t0 + tl)) * QKV_N + 2 * D_MODEL + h * D_HEAD + dg * 8];
    }
    __syncthreads();
#pragma unroll
    for (int ii = 0; ii < 2; ii++) {
        int d = (tid >> 3) + 32 * ii, tg = tid & 7;
        bf16x8 v;
#pragma unroll
        for (int j = 0; j < 8; j++) v[j] = S[tg * 8 + j][d];
        *(bf16x8*)&vt[((size_t)bh * 64 + d) * SEQ + t0 + tg * 8] = v;
    }
}

// ---------------------------------------------------------------------------
// Flash attention, 32x32 MFMA, LPT-ordered flat grid (unchanged from R8).
// ---------------------------------------------------------------------------
__device__ __forceinline__ unsigned cvt_pk_bf16(float lo, float hi) {
    unsigned r;
    asm("v_cvt_pk_bf16_f32 %0, %1, %2" : "=v"(r) : "v"(lo), "v"(hi));
    return r;
}

__global__ __launch_bounds__(256) void attn_fwd(const short* __restrict__ qkv,
                                                const short* __restrict__ vt,
                                                unsigned short* __restrict__ out) {
    __shared__ __align__(16) short Ks[64][64];
    __shared__ __align__(16) short Vs[64][64];

    const int tid  = threadIdx.x;
    const int w    = tid >> 6;
    const int lane = tid & 63;
    const int l31  = lane & 31;
    const int hi   = lane >> 5;
    const int swzk = SWZ(l31);
    const int flat = blockIdx.x;
    const int i    = 31 - flat / NBH;
    const int bh   = flat % NBH;
    const int b    = bh / N_HEADS, h = bh % N_HEADS;
    const size_t rowbase = (size_t)b * SEQ;
    const int q0   = i * 128;
    const int qw   = q0 + w * 32;
    const int qg   = qw + l31;
    const int srow = tid >> 3, sg = tid & 7;

    bf16x8 qf[4];
    {
        const short* qp = &qkv[(rowbase + qg) * QKV_N + h * D_HEAD + hi * 8];
#pragma unroll
        for (int c = 0; c < 4; c++) qf[c] = *(const bf16x8*)&qp[c * 16];
    }

    float m_ = -INFINITY, l_ = 0.0f;
    f32x16 oacc[2];
#pragma unroll
    for (int nd = 0; nd < 2; nd++)
#pragma unroll
        for (int e = 0; e < 16; e++) oacc[nd][e] = 0.0f;

    const int nj = 2 * i + 2;

    bf16x8 kp[2], vp[2];
#pragma unroll
    for (int s = 0; s < 2; s++) {
        int row = srow + 32 * s;
        kp[s] = *(const bf16x8*)&qkv[(rowbase + row) * QKV_N + D_MODEL + h * D_HEAD + sg * 8];
        vp[s] = *(const bf16x8*)&vt[((size_t)bh * 64 + row) * SEQ + sg * 8];
    }

    for (int jt = 0; jt < nj; jt++) {
        const int j0 = jt * 64;
        __syncthreads();
#pragma unroll
        for (int s = 0; s < 2; s++) {
            int row = srow + 32 * s;
            int dst = (sg ^ SWZ(row)) * 8;
            *(bf16x8*)&Ks[row][dst] = kp[s];
            *(bf16x8*)&Vs[row][dst] = vp[s];
        }
        {
            int jn = (jt + 1 < nj) ? j0 + 64 : 0;
#pragma unroll
            for (int s = 0; s < 2; s++) {
                int row = srow + 32 * s;
                kp[s] = *(const bf16x8*)&qkv[(rowbase + jn + row) * QKV_N + D_MODEL + h * D_HEAD + sg * 8];
                vp[s] = *(const bf16x8*)&vt[((size_t)bh * 64 + row) * SEQ + jn + sg * 8];
            }
        }
        __syncthreads();

        if (j0 > qw + 31) continue;
        const bool skip1 = (j0 >= qw);

        f32x16 sa0, sa1;
#pragma unroll
        for (int e = 0; e < 16; e++) { sa0[e] = 0.0f; sa1[e] = 0.0f; }
        __builtin_amdgcn_s_setprio(1);
#pragma unroll
        for (int c = 0; c < 4; c++) {
            bf16x8 kf0 = *(const bf16x8*)&Ks[l31][((2 * c + hi) ^ swzk) * 8];
            sa0 = __builtin_amdgcn_mfma_f32_32x32x16_bf16(kf0, qf[c], sa0, 0, 0, 0);
        }
        if (!skip1) {
#pragma unroll
            for (int c = 0; c < 4; c++) {
                bf16x8 kf1 = *(const bf16x8*)&Ks[32 + l31][((2 * c + hi) ^ swzk) * 8];
                sa1 = __builtin_amdgcn_mfma_f32_32x32x16_bf16(kf1, qf[c], sa1, 0, 0, 0);
            }
        }
        __builtin_amdgcn_s_setprio(0);

        if (j0 + 63 > qw) {
#pragma unroll
            for (int g = 0; g < 4; g++)
#pragma unroll
                for (int r = 0; r < 4; r++) {
                    int kloc = r + 8 * g + 4 * hi;
                    if (j0 + kloc > qg) sa0[g * 4 + r] = -INFINITY;
                    if (!skip1 && j0 + 32 + kloc > qg) sa1[g * 4 + r] = -INFINITY;
                }
        }

        float mx;
        {
            float p0 = sa0[0], p1 = sa0[1], p2 = sa0[2], p3 = sa0[3];
#pragma unroll
            for (int e = 4; e < 16; e += 4) {
                p0 = fmaxf(p0, sa0[e]); p1 = fmaxf(p1, sa0[e + 1]);
                p2 = fmaxf(p2, sa0[e + 2]); p3 = fmaxf(p3, sa0[e + 3]);
            }
            if (!skip1) {
#pragma unroll
                for (int e = 0; e < 16; e += 4) {
                    p0 = fmaxf(p0, sa1[e]); p1 = fmaxf(p1, sa1[e + 1]);
                    p2 = fmaxf(p2, sa1[e + 2]); p3 = fmaxf(p3, sa1[e + 3]);
                }
            }
            mx = fmaxf(fmaxf(p0, p1), fmaxf(p2, p3));
        }
        mx = fmaxf(mx, __shfl_xor(mx, 32, 64));
        float smax = mx * SCL;

        if (!__all(smax <= m_ + 8.0f)) {
            float mnew = fmaxf(m_, smax);
            float corr = __builtin_amdgcn_exp2f(m_ - mnew);
            m_ = mnew;
            l_ *= corr;
#pragma unroll
            for (int g = 0; g < 4; g++)
#pragma unroll
                for (int r = 0; r < 4; r++) {
                    float cf = __shfl(corr, r + 8 * g + 4 * hi, 64);
                    oacc[0][g * 4 + r] *= cf;
                    oacc[1][g * 4 + r] *= cf;
                }
        }

        float s0 = 0.f, s1 = 0.f, s2 = 0.f, s3 = 0.f;
#pragma unroll
        for (int e = 0; e < 16; e += 4) {
            float a0 = __builtin_amdgcn_exp2f(fmaf(sa0[e], SCL, -m_));
            float a1 = __builtin_amdgcn_exp2f(fmaf(sa0[e + 1], SCL, -m_));
            float a2 = __builtin_amdgcn_exp2f(fmaf(sa0[e + 2], SCL, -m_));
            float a3 = __builtin_amdgcn_exp2f(fmaf(sa0[e + 3], SCL, -m_));
            sa0[e] = a0; sa0[e + 1] = a1; sa0[e + 2] = a2; sa0[e + 3] = a3;
            s0 += a0; s1 += a1; s2 += a2; s3 += a3;
        }
        if (!skip1) {
#pragma unroll
            for (int e = 0; e < 16; e += 4) {
                float a0 = __builtin_amdgcn_exp2f(fmaf(sa1[e], SCL, -m_));
                float a1 = __builtin_amdgcn_exp2f(fmaf(sa1[e + 1], SCL, -m_));
                float a2 = __builtin_amdgcn_exp2f(fmaf(sa1[e + 2], SCL, -m_));
                float a3 = __builtin_amdgcn_exp2f(fmaf(sa1[e + 3], SCL, -m_));
                sa1[e] = a0; sa1[e + 1] = a1; sa1[e + 2] = a2; sa1[e + 3] = a3;
                s0 += a0; s1 += a1; s2 += a2; s3 += a3;
            }
        }
        float ls = (s0 + s1) + (s2 + s3);
        ls += __shfl_xor(ls, 32, 64);
        l_ += ls;

        bf16x8 pa0, pa1, pa2, pa3;
        {
            unsigned X[4], U[4];
#pragma unroll
            for (int g = 0; g < 4; g++) {
                X[g] = cvt_pk_bf16(sa0[4 * g + 0], sa0[4 * g + 1]);
                U[g] = cvt_pk_bf16(sa0[4 * g + 2], sa0[4 * g + 3]);
            }
            asm("v_permlane32_swap_b32 %0, %1" : "+v"(X[0]), "+v"(X[1]));
            asm("v_permlane32_swap_b32 %0, %1" : "+v"(U[0]), "+v"(U[1]));
            asm("v_permlane32_swap_b32 %0, %1" : "+v"(X[2]), "+v"(X[3]));
            asm("v_permlane32_swap_b32 %0, %1" : "+v"(U[2]), "+v"(U[3]));
            union { unsigned u[4]; bf16x8 v; } q0_, q1_;
            q0_.u[0] = X[0]; q0_.u[1] = U[0]; q0_.u[2] = X[1]; q0_.u[3] = U[1];
            q1_.u[0] = X[2]; q1_.u[1] = U[2]; q1_.u[2] = X[3]; q1_.u[3] = U[3];
            pa0 = q0_.v; pa1 = q1_.v;
        }
        if (!skip1) {
            unsigned X[4], U[4];
#pragma unroll
            for (int g = 0; g < 4; g++) {
                X[g] = cvt_pk_bf16(sa1[4 * g + 0], sa1[4 * g + 1]);
                U[g] = cvt_pk_bf16(sa1[4 * g + 2], sa1[4 * g + 3]);
            }
            asm("v_permlane32_swap_b32 %0, %1" : "+v"(X[0]), "+v"(X[1]));
            asm("v_permlane32_swap_b32 %0, %1" : "+v"(U[0]), "+v"(U[1]));
            asm("v_permlane32_swap_b32 %0, %1" : "+v"(X[2]), "+v"(X[3]));
            asm("v_permlane32_swap_b32 %0, %1" : "+v"(U[2]), "+v"(U[3]));
            union { unsigned u[4]; bf16x8 v; } q0_, q1_;
            q0_.u[0] = X[0]; q0_.u[1] = U[0]; q0_.u[2] = X[1]; q0_.u[3] = U[1];
            q1_.u[0] = X[2]; q1_.u[1] = U[2]; q1_.u[2] = X[3]; q1_.u[3] = U[3];
            pa2 = q0_.v; pa3 = q1_.v;
        } else {
            pa2 = pa0; pa3 = pa1;
        }

        __builtin_amdgcn_s_setprio(1);
#pragma unroll
        for (int nd = 0; nd < 2; nd++) {
            const int vrow = nd * 32 + l31;
            const int vswz = SWZ(vrow);
            bf16x8 vb0 = *(const bf16x8*)&Vs[vrow][((0 + hi) ^ vswz) * 8];
            oacc[nd] = __builtin_amdgcn_mfma_f32_32x32x16_bf16(pa0, vb0, oacc[nd], 0, 0, 0);
            bf16x8 vb1 = *(const bf16x8*)&Vs[vrow][((2 + hi) ^ vswz) * 8];
            oacc[nd] = __builtin_amdgcn_mfma_f32_32x32x16_bf16(pa1, vb1, oacc[nd], 0, 0, 0);
            if (!skip1) {
                bf16x8 vb2 = *(const bf16x8*)&Vs[vrow][((4 + hi) ^ vswz) * 8];
                oacc[nd] = __builtin_amdgcn_mfma_f32_32x32x16_bf16(pa2, vb2, oacc[nd], 0, 0, 0);
                bf16x8 vb3 = *(const bf16x8*)&Vs[vrow][((6 + hi) ^ vswz) * 8];
                oacc[nd] = __builtin_amdgcn_mfma_f32_32x32x16_bf16(pa3, vb3, oacc[nd], 0, 0, 0);
            }
        }
        __builtin_amdgcn_s_setprio(0);
    }

    float li = 1.0f / l_;
    float lT[16];
#pragma unroll
    for (int g = 0; g < 4; g++)
#pragma unroll
        for (int r = 0; r < 4; r++) lT[g * 4 + r] = __shfl(li, r + 8 * g + 4 * hi, 64);
#pragma unroll
    for (int nd = 0; nd < 2; nd++)
#pragma unroll
        for (int g = 0; g < 4; g++)
#pragma unroll
            for (int r = 0; r < 4; r++) {
                int qrow = qw + r + 8 * g + 4 * hi;
                out[(rowbase + qrow) * D_MODEL + h * D_HEAD + nd * 32 + l31] =
                    __bfloat16_as_ushort(__float2bfloat16(oacc[nd][g * 4 + r] * lT[g * 4 + r]));
            }
}

// ---------------------------------------------------------------------------
extern "C" void kernel_launch(void* const* d_in, const int* in_sizes, int n_in,
                              void* d_out, int out_size, void* d_ws, size_t ws_size,
                              hipStream_t stream) {
    const float* x     = (const float*)d_in[0];
    const float* w_qkv = (const float*)d_in[1];
    const float* w_out = (const float*)d_in[2];
    float* outp        = (float*)d_out;

    char* ws = (char*)d_ws;
    size_t off = 0;
    auto alloc = [&](size_t bytes) -> void* {
        void* p = ws + off;
        off = (off + bytes + 255) & ~(size_t)255;
        return p;
    };
    unsigned short* xb    = (unsigned short*)alloc((size_t)MROWS * D_MODEL * 2);  // also attn out
    unsigned short* wqkvb = (unsigned short*)alloc((size_t)QKV_N * D_MODEL * 2);
    unsigned short* woutb = (unsigned short*)alloc((size_t)D_MODEL * D_MODEL * 2);
    unsigned short* qkvb  = (unsigned short*)alloc((size_t)MROWS * QKV_N * 2);
    unsigned short* vtb   = (unsigned short*)alloc((size_t)BATCH * N_HEADS * D_HEAD * SEQ * 2);

    {
        const int nx4 = MROWS * D_MODEL / 4;
        const int nq4 = QKV_N * D_MODEL / 4;
        const int no4 = D_MODEL * D_MODEL / 4;
        const int tot = nx4 + nq4 + no4;
        cvt_all<<<(tot + 255) / 256, 256, 0, stream>>>(x, xb, nx4, w_qkv, wqkvb, nq4, w_out, woutb, no4);
    }

    // qkv = x @ w_qkv^T   (M=8192, N=2304, K=768) -> bf16
    gemm_bt<false><<<dim3(QKV_N / BN, MROWS / BM), 256, 0, stream>>>(
        (const short*)xb, (const short*)wqkvb, nullptr, qkvb, MROWS, QKV_N, D_MODEL);

    // V transpose: (b,t,h,d) -> [bh*64+d][t]
    v_transpose<<<dim3(SEQ / 64, BATCH * N_HEADS), 256, 0, stream>>>((const short*)qkvb, (short*)vtb);

    // attention: flat LPT grid, heaviest q-blocks first
    attn_fwd<<<dim3(32 * NBH), 256, 0, stream>>>(
        (const short*)qkvb, (const short*)vtb, xb);

    // out = attn @ w_out^T  (M=8192, N=768, K=768) -> f32
    gemm_bt<true><<<dim3(D_MODEL / BN, MROWS / BM), 256, 0, stream>>>(
        (const short*)xb, (const short*)woutb, outp, nullptr, MROWS, D_MODEL, D_MODEL);
}

// Round 10
// 203.885 us; speedup vs baseline: 8.2159x; 1.0119x over previous
//
#include <hip/hip_runtime.h>
#include <hip/hip_bf16.h>

typedef __attribute__((ext_vector_type(8))) short bf16x8;
typedef __attribute__((ext_vector_type(4))) float f32x4;
typedef __attribute__((ext_vector_type(16))) float f32x16;

#define D_MODEL 768
#define N_HEADS 12
#define D_HEAD  64
#define SEQ     4096
#define BATCH   2
#define MROWS   (BATCH * SEQ)          // 8192
#define QKV_N   (3 * D_MODEL)          // 2304
#define NBH     (BATCH * N_HEADS)      // 24
#define SCL     0.18033688011112042f   // (1/8) * log2(e)

// LDS granule swizzle for attn tiles (rows {s,s+8,s+16,s+24} must differ)
#define SWZ(row) ((((row) & 7) ^ (((row) >> 3) & 3)))

// global_load_lds (LDS dest wave-uniform; lane adds lane*16)
#define GLOAD_LDS16(gsrc, ldst) \
    __builtin_amdgcn_global_load_lds( \
        (const __attribute__((address_space(1))) int*)(gsrc), \
        (__attribute__((address_space(3))) int*)(ldst), 16, 0, 0)

// ---------------------------------------------------------------------------
// fused f32 -> bf16 conversion for all three inputs
// ---------------------------------------------------------------------------
__global__ __launch_bounds__(256) void cvt_all(const float* __restrict__ x,  unsigned short* __restrict__ xb,  int nx4,
                                               const float* __restrict__ wq, unsigned short* __restrict__ wqb, int nq4,
                                               const float* __restrict__ wo, unsigned short* __restrict__ wob, int no4) {
    int i = blockIdx.x * blockDim.x + threadIdx.x;
    const float* in;
    unsigned short* out;
    int idx;
    if (i < nx4)                   { in = x;  out = xb;  idx = i; }
    else if (i < nx4 + nq4)        { in = wq; out = wqb; idx = i - nx4; }
    else if (i < nx4 + nq4 + no4)  { in = wo; out = wob; idx = i - nx4 - nq4; }
    else return;
    const float4 v = *(const float4*)(in + (size_t)idx * 4);
    ushort4 o;
    o.x = __bfloat16_as_ushort(__float2bfloat16(v.x));
    o.y = __bfloat16_as_ushort(__float2bfloat16(v.y));
    o.z = __bfloat16_as_ushort(__float2bfloat16(v.z));
    o.w = __bfloat16_as_ushort(__float2bfloat16(v.w));
    *(ushort4*)(out + (size_t)idx * 4) = o;
}

// ---------------------------------------------------------------------------
// GEMM: C[M,N] = A[M,K] * B[N,K]^T  (bf16, f32 acc), 128x128 tile, BK=64.
// global_load_lds staging (linear LDS + pre-swizzled global source).
// WRITE_VT: V-region columns (col >= 2*D_MODEL) go straight to the
// transposed V buffer vt[bh*64+d][t] as ushort4 (fused v_transpose).
// ---------------------------------------------------------------------------
#define BM 128
#define BN 128
#define BK 64

template <bool OUT_F32, bool WRITE_VT>
__global__ __launch_bounds__(256) void gemm_bt(const short* __restrict__ A,
                                               const short* __restrict__ B,
                                               float* __restrict__ Cf,
                                               unsigned short* __restrict__ Cb,
                                               unsigned short* __restrict__ vt,
                                               int M, int N, int K) {
    __shared__ __align__(16) short As[BM][BK];
    __shared__ __align__(16) short Bs[BN][BK];

    const int tid  = threadIdx.x;
    const int m0   = blockIdx.y * BM;
    const int n0   = blockIdx.x * BN;
    const int w    = tid >> 6;
    const int lane = tid & 63;
    const int wr   = w >> 1, wc = w & 1;
    const int lr   = lane & 15, lhi = lane >> 4;

    int srow[4], sga[4];
#pragma unroll
    for (int s = 0; s < 4; s++) {
        int idx = (w * 4 + s) * 64 + lane;
        srow[s] = idx >> 3;
        sga[s]  = (idx & 7) ^ (srow[s] & 7);
    }

    f32x4 acc[4][4];
#pragma unroll
    for (int i = 0; i < 4; i++)
#pragma unroll
        for (int j = 0; j < 4; j++)
#pragma unroll
            for (int e = 0; e < 4; e++) acc[i][j][e] = 0.0f;

    for (int k0 = 0; k0 < K; k0 += BK) {
#pragma unroll
        for (int s = 0; s < 4; s++) {
            GLOAD_LDS16(&A[(size_t)(m0 + srow[s]) * K + k0 + sga[s] * 8],
                        (short*)As + (w * 4 + s) * 512);
            GLOAD_LDS16(&B[(size_t)(n0 + srow[s]) * K + k0 + sga[s] * 8],
                        (short*)Bs + (w * 4 + s) * 512);
        }
        __syncthreads();
#pragma unroll
        for (int c = 0; c < 2; ++c) {
            bf16x8 af[4], bfr[4];
#pragma unroll
            for (int mi = 0; mi < 4; mi++) {
                int row = wr * 64 + mi * 16 + lr;
                af[mi] = *(const bf16x8*)&As[row][((c * 4 + lhi) ^ (lr & 7)) * 8];
            }
#pragma unroll
            for (int ni = 0; ni < 4; ni++) {
                int row = wc * 64 + ni * 16 + lr;
                bfr[ni] = *(const bf16x8*)&Bs[row][((c * 4 + lhi) ^ (lr & 7)) * 8];
            }
#pragma unroll
            for (int mi = 0; mi < 4; mi++)
#pragma unroll
                for (int ni = 0; ni < 4; ni++)
                    acc[mi][ni] = __builtin_amdgcn_mfma_f32_16x16x32_bf16(af[mi], bfr[ni], acc[mi][ni], 0, 0, 0);
        }
        __syncthreads();
    }

#pragma unroll
    for (int mi = 0; mi < 4; mi++)
#pragma unroll
        for (int ni = 0; ni < 4; ni++) {
            const int col  = n0 + wc * 64 + ni * 16 + lr;
            const int row0 = m0 + wr * 64 + mi * 16 + lhi * 4;
            if (WRITE_VT && col >= 2 * D_MODEL) {
                // V region -> transposed store (4 consecutive t per lane, 8B)
                const int hd = col - 2 * D_MODEL;
                const int h2 = hd >> 6, d = hd & 63;
                const int b2 = row0 >> 12, t = row0 & (SEQ - 1);
                ushort4 p;
                p.x = __bfloat16_as_ushort(__float2bfloat16(acc[mi][ni][0]));
                p.y = __bfloat16_as_ushort(__float2bfloat16(acc[mi][ni][1]));
                p.z = __bfloat16_as_ushort(__float2bfloat16(acc[mi][ni][2]));
                p.w = __bfloat16_as_ushort(__float2bfloat16(acc[mi][ni][3]));
                *(ushort4*)&vt[((size_t)(b2 * N_HEADS + h2) * 64 + d) * SEQ + t] = p;
            } else {
#pragma unroll
                for (int r = 0; r < 4; r++) {
                    float v = acc[mi][ni][r];
                    if (OUT_F32)
                        Cf[(size_t)(row0 + r) * N + col] = v;
                    else
                        Cb[(size_t)(row0 + r) * N + col] = __bfloat16_as_ushort(__float2bfloat16(v));
                }
            }
        }
}

// ---------------------------------------------------------------------------
// Flash attention, 32x32 MFMA, LPT-ordered flat grid.
// l computed via MFMA against ones-B (lands in oacc-land, no shuffles).
// ---------------------------------------------------------------------------
__device__ __forceinline__ unsigned cvt_pk_bf16(float lo, float hi) {
    unsigned r;
    asm("v_cvt_pk_bf16_f32 %0, %1, %2" : "=v"(r) : "v"(lo), "v"(hi));
    return r;
}

__global__ __launch_bounds__(256) void attn_fwd(const short* __restrict__ qkv,
                                                const short* __restrict__ vt,
                                                unsigned short* __restrict__ out) {
    __shared__ __align__(16) short Ks[64][64];
    __shared__ __align__(16) short Vs[64][64];

    const int tid  = threadIdx.x;
    const int w    = tid >> 6;
    const int lane = tid & 63;
    const int l31  = lane & 31;
    const int hi   = lane >> 5;
    const int swzk = SWZ(l31);
    const int flat = blockIdx.x;
    const int i    = 31 - flat / NBH;
    const int bh   = flat % NBH;
    const int b    = bh / N_HEADS, h = bh % N_HEADS;
    const size_t rowbase = (size_t)b * SEQ;
    const int q0   = i * 128;
    const int qw   = q0 + w * 32;
    const int qg   = qw + l31;
    const int srow = tid >> 3, sg = tid & 7;

    bf16x8 ones;
#pragma unroll
    for (int j = 0; j < 8; j++) ones[j] = (short)0x3F80;   // bf16 1.0

    bf16x8 qf[4];
    {
        const short* qp = &qkv[(rowbase + qg) * QKV_N + h * D_HEAD + hi * 8];
#pragma unroll
        for (int c = 0; c < 4; c++) qf[c] = *(const bf16x8*)&qp[c * 16];
    }

    float m_ = -INFINITY;
    f32x16 oacc[2], lacc;
#pragma unroll
    for (int e = 0; e < 16; e++) { oacc[0][e] = 0.0f; oacc[1][e] = 0.0f; lacc[e] = 0.0f; }

    const int nj = 2 * i + 2;

    bf16x8 kp[2], vp[2];
#pragma unroll
    for (int s = 0; s < 2; s++) {
        int row = srow + 32 * s;
        kp[s] = *(const bf16x8*)&qkv[(rowbase + row) * QKV_N + D_MODEL + h * D_HEAD + sg * 8];
        vp[s] = *(const bf16x8*)&vt[((size_t)bh * 64 + row) * SEQ + sg * 8];
    }

    for (int jt = 0; jt < nj; jt++) {
        const int j0 = jt * 64;
        __syncthreads();
#pragma unroll
        for (int s = 0; s < 2; s++) {
            int row = srow + 32 * s;
            int dst = (sg ^ SWZ(row)) * 8;
            *(bf16x8*)&Ks[row][dst] = kp[s];
            *(bf16x8*)&Vs[row][dst] = vp[s];
        }
        {
            int jn = (jt + 1 < nj) ? j0 + 64 : 0;
#pragma unroll
            for (int s = 0; s < 2; s++) {
                int row = srow + 32 * s;
                kp[s] = *(const bf16x8*)&qkv[(rowbase + jn + row) * QKV_N + D_MODEL + h * D_HEAD + sg * 8];
                vp[s] = *(const bf16x8*)&vt[((size_t)bh * 64 + row) * SEQ + jn + sg * 8];
            }
        }
        __syncthreads();

        if (j0 > qw + 31) continue;
        const bool skip1 = (j0 >= qw);

        // ---- S^T = K · Q^T ----
        f32x16 sa0, sa1;
#pragma unroll
        for (int e = 0; e < 16; e++) { sa0[e] = 0.0f; sa1[e] = 0.0f; }
        __builtin_amdgcn_s_setprio(1);
#pragma unroll
        for (int c = 0; c < 4; c++) {
            bf16x8 kf0 = *(const bf16x8*)&Ks[l31][((2 * c + hi) ^ swzk) * 8];
            sa0 = __builtin_amdgcn_mfma_f32_32x32x16_bf16(kf0, qf[c], sa0, 0, 0, 0);
        }
        if (!skip1) {
#pragma unroll
            for (int c = 0; c < 4; c++) {
                bf16x8 kf1 = *(const bf16x8*)&Ks[32 + l31][((2 * c + hi) ^ swzk) * 8];
                sa1 = __builtin_amdgcn_mfma_f32_32x32x16_bf16(kf1, qf[c], sa1, 0, 0, 0);
            }
        }
        __builtin_amdgcn_s_setprio(0);

        // ---- causal mask ----
        if (j0 + 63 > qw) {
#pragma unroll
            for (int g = 0; g < 4; g++)
#pragma unroll
                for (int r = 0; r < 4; r++) {
                    int kloc = r + 8 * g + 4 * hi;
                    if (j0 + kloc > qg) sa0[g * 4 + r] = -INFINITY;
                    if (!skip1 && j0 + 32 + kloc > qg) sa1[g * 4 + r] = -INFINITY;
                }
        }

        // ---- row max (max3-fusable tree) ----
        float mx;
        {
            float p0 = fmaxf(sa0[0], sa0[1]), p1 = fmaxf(sa0[2], sa0[3]);
            p0 = fmaxf(fmaxf(sa0[4], sa0[5]), p0);
            p1 = fmaxf(fmaxf(sa0[6], sa0[7]), p1);
            p0 = fmaxf(fmaxf(sa0[8], sa0[9]), p0);
            p1 = fmaxf(fmaxf(sa0[10], sa0[11]), p1);
            p0 = fmaxf(fmaxf(sa0[12], sa0[13]), p0);
            p1 = fmaxf(fmaxf(sa0[14], sa0[15]), p1);
            if (!skip1) {
                p0 = fmaxf(fmaxf(sa1[0], sa1[1]), p0);
                p1 = fmaxf(fmaxf(sa1[2], sa1[3]), p1);
                p0 = fmaxf(fmaxf(sa1[4], sa1[5]), p0);
                p1 = fmaxf(fmaxf(sa1[6], sa1[7]), p1);
                p0 = fmaxf(fmaxf(sa1[8], sa1[9]), p0);
                p1 = fmaxf(fmaxf(sa1[10], sa1[11]), p1);
                p0 = fmaxf(fmaxf(sa1[12], sa1[13]), p0);
                p1 = fmaxf(fmaxf(sa1[14], sa1[15]), p1);
            }
            mx = fmaxf(p0, p1);
        }
        mx = fmaxf(mx, __shfl_xor(mx, 32, 64));
        float smax = mx * SCL;

        // T13 defer-max
        if (!__all(smax <= m_ + 8.0f)) {
            float mnew = fmaxf(m_, smax);
            float corr = __builtin_amdgcn_exp2f(m_ - mnew);
            m_ = mnew;
#pragma unroll
            for (int g = 0; g < 4; g++)
#pragma unroll
                for (int r = 0; r < 4; r++) {
                    float cf = __shfl(corr, r + 8 * g + 4 * hi, 64);
                    oacc[0][g * 4 + r] *= cf;
                    oacc[1][g * 4 + r] *= cf;
                    lacc[g * 4 + r] *= cf;
                }
        }

        // ---- P = exp2(S*SCL - m) (no VALU row-sum; l via MFMA below) ----
#pragma unroll
        for (int e = 0; e < 16; e += 4) {
            sa0[e]     = __builtin_amdgcn_exp2f(fmaf(sa0[e], SCL, -m_));
            sa0[e + 1] = __builtin_amdgcn_exp2f(fmaf(sa0[e + 1], SCL, -m_));
            sa0[e + 2] = __builtin_amdgcn_exp2f(fmaf(sa0[e + 2], SCL, -m_));
            sa0[e + 3] = __builtin_amdgcn_exp2f(fmaf(sa0[e + 3], SCL, -m_));
        }
        if (!skip1) {
#pragma unroll
            for (int e = 0; e < 16; e += 4) {
                sa1[e]     = __builtin_amdgcn_exp2f(fmaf(sa1[e], SCL, -m_));
                sa1[e + 1] = __builtin_amdgcn_exp2f(fmaf(sa1[e + 1], SCL, -m_));
                sa1[e + 2] = __builtin_amdgcn_exp2f(fmaf(sa1[e + 2], SCL, -m_));
                sa1[e + 3] = __builtin_amdgcn_exp2f(fmaf(sa1[e + 3], SCL, -m_));
            }
        }

        // ---- pack P -> bf16 A-frags (static; named pa0..pa3) ----
        bf16x8 pa0, pa1, pa2, pa3;
        {
            unsigned X[4], U[4];
#pragma unroll
            for (int g = 0; g < 4; g++) {
                X[g] = cvt_pk_bf16(sa0[4 * g + 0], sa0[4 * g + 1]);
                U[g] = cvt_pk_bf16(sa0[4 * g + 2], sa0[4 * g + 3]);
            }
            asm("v_permlane32_swap_b32 %0, %1" : "+v"(X[0]), "+v"(X[1]));
            asm("v_permlane32_swap_b32 %0, %1" : "+v"(U[0]), "+v"(U[1]));
            asm("v_permlane32_swap_b32 %0, %1" : "+v"(X[2]), "+v"(X[3]));
            asm("v_permlane32_swap_b32 %0, %1" : "+v"(U[2]), "+v"(U[3]));
            union { unsigned u[4]; bf16x8 v; } q0_, q1_;
            q0_.u[0] = X[0]; q0_.u[1] = U[0]; q0_.u[2] = X[1]; q0_.u[3] = U[1];
            q1_.u[0] = X[2]; q1_.u[1] = U[2]; q1_.u[2] = X[3]; q1_.u[3] = U[3];
            pa0 = q0_.v; pa1 = q1_.v;
        }
        if (!skip1) {
            unsigned X[4], U[4];
#pragma unroll
            for (int g = 0; g < 4; g++) {
                X[g] = cvt_pk_bf16(sa1[4 * g + 0], sa1[4 * g + 1]);
                U[g] = cvt_pk_bf16(sa1[4 * g + 2], sa1[4 * g + 3]);
            }
            asm("v_permlane32_swap_b32 %0, %1" : "+v"(X[0]), "+v"(X[1]));
            asm("v_permlane32_swap_b32 %0, %1" : "+v"(U[0]), "+v"(U[1]));
            asm("v_permlane32_swap_b32 %0, %1" : "+v"(X[2]), "+v"(X[3]));
            asm("v_permlane32_swap_b32 %0, %1" : "+v"(U[2]), "+v"(U[3]));
            union { unsigned u[4]; bf16x8 v; } q0_, q1_;
            q0_.u[0] = X[0]; q0_.u[1] = U[0]; q0_.u[2] = X[1]; q0_.u[3] = U[1];
            q1_.u[0] = X[2]; q1_.u[1] = U[2]; q1_.u[2] = X[3]; q1_.u[3] = U[3];
            pa2 = q0_.v; pa3 = q1_.v;
        } else {
            pa2 = pa0; pa3 = pa1;
        }

        // ---- O += P·V and l += P·1 ----
        __builtin_amdgcn_s_setprio(1);
        lacc = __builtin_amdgcn_mfma_f32_32x32x16_bf16(pa0, ones, lacc, 0, 0, 0);
        lacc = __builtin_amdgcn_mfma_f32_32x32x16_bf16(pa1, ones, lacc, 0, 0, 0);
        if (!skip1) {
            lacc = __builtin_amdgcn_mfma_f32_32x32x16_bf16(pa2, ones, lacc, 0, 0, 0);
            lacc = __builtin_amdgcn_mfma_f32_32x32x16_bf16(pa3, ones, lacc, 0, 0, 0);
        }
#pragma unroll
        for (int nd = 0; nd < 2; nd++) {
            const int vrow = nd * 32 + l31;
            const int vswz = SWZ(vrow);
            bf16x8 vb0 = *(const bf16x8*)&Vs[vrow][((0 + hi) ^ vswz) * 8];
            oacc[nd] = __builtin_amdgcn_mfma_f32_32x32x16_bf16(pa0, vb0, oacc[nd], 0, 0, 0);
            bf16x8 vb1 = *(const bf16x8*)&Vs[vrow][((2 + hi) ^ vswz) * 8];
            oacc[nd] = __builtin_amdgcn_mfma_f32_32x32x16_bf16(pa1, vb1, oacc[nd], 0, 0, 0);
            if (!skip1) {
                bf16x8 vb2 = *(const bf16x8*)&Vs[vrow][((4 + hi) ^ vswz) * 8];
                oacc[nd] = __builtin_amdgcn_mfma_f32_32x32x16_bf16(pa2, vb2, oacc[nd], 0, 0, 0);
                bf16x8 vb3 = *(const bf16x8*)&Vs[vrow][((6 + hi) ^ vswz) * 8];
                oacc[nd] = __builtin_amdgcn_mfma_f32_32x32x16_bf16(pa3, vb3, oacc[nd], 0, 0, 0);
            }
        }
        __builtin_amdgcn_s_setprio(0);
    }

    // ---- epilogue: per-element 1/l (replicated across cols, no shuffles) ----
#pragma unroll
    for (int e = 0; e < 16; e++) lacc[e] = __builtin_amdgcn_rcpf(lacc[e]);
#pragma unroll
    for (int nd = 0; nd < 2; nd++)
#pragma unroll
        for (int g = 0; g < 4; g++)
#pragma unroll
            for (int r = 0; r < 4; r++) {
                int qrow = qw + r + 8 * g + 4 * hi;
                out[(rowbase + qrow) * D_MODEL + h * D_HEAD + nd * 32 + l31] =
                    __bfloat16_as_ushort(__float2bfloat16(oacc[nd][g * 4 + r] * lacc[g * 4 + r]));
            }
}

// ---------------------------------------------------------------------------
extern "C" void kernel_launch(void* const* d_in, const int* in_sizes, int n_in,
                              void* d_out, int out_size, void* d_ws, size_t ws_size,
                              hipStream_t stream) {
    const float* x     = (const float*)d_in[0];
    const float* w_qkv = (const float*)d_in[1];
    const float* w_out = (const float*)d_in[2];
    float* outp        = (float*)d_out;

    char* ws = (char*)d_ws;
    size_t off = 0;
    auto alloc = [&](size_t bytes) -> void* {
        void* p = ws + off;
        off = (off + bytes + 255) & ~(size_t)255;
        return p;
    };
    unsigned short* xb    = (unsigned short*)alloc((size_t)MROWS * D_MODEL * 2);  // also attn out
    unsigned short* wqkvb = (unsigned short*)alloc((size_t)QKV_N * D_MODEL * 2);
    unsigned short* woutb = (unsigned short*)alloc((size_t)D_MODEL * D_MODEL * 2);
    unsigned short* qkvb  = (unsigned short*)alloc((size_t)MROWS * QKV_N * 2);
    unsigned short* vtb   = (unsigned short*)alloc((size_t)BATCH * N_HEADS * D_HEAD * SEQ * 2);

    {
        const int nx4 = MROWS * D_MODEL / 4;
        const int nq4 = QKV_N * D_MODEL / 4;
        const int no4 = D_MODEL * D_MODEL / 4;
        const int tot = nx4 + nq4 + no4;
        cvt_all<<<(tot + 255) / 256, 256, 0, stream>>>(x, xb, nx4, w_qkv, wqkvb, nq4, w_out, woutb, no4);
    }

    // qkv = x @ w_qkv^T ; V-region written transposed to vtb (fused)
    gemm_bt<false, true><<<dim3(QKV_N / BN, MROWS / BM), 256, 0, stream>>>(
        (const short*)xb, (const short*)wqkvb, nullptr, qkvb, vtb, MROWS, QKV_N, D_MODEL);

    // attention: flat LPT grid, heaviest q-blocks first
    attn_fwd<<<dim3(32 * NBH), 256, 0, stream>>>(
        (const short*)qkvb, (const short*)vtb, xb);

    // out = attn @ w_out^T  (M=8192, N=768, K=768) -> f32
    gemm_bt<true, false><<<dim3(D_MODEL / BN, MROWS / BM), 256, 0, stream>>>(
        (const short*)xb, (const short*)woutb, outp, nullptr, nullptr, MROWS, D_MODEL, D_MODEL);
}